// Round 18
// baseline (214.104 us; speedup 1.0000x reference)
//
#include <hip/hip_runtime.h>

typedef float v2f __attribute__((ext_vector_type(2)));
typedef float v4f __attribute__((ext_vector_type(4)));

#define N_ROWS 131072
#define DIM    256
#define KP     16
#define NDOM   8
#define NB     32      // bins
#define GG     100     // barycenter grid

#define EB_N   (NDOM*KP*(NB+1))   // 4224 floats
#define BARY_N (KP*GG)            // 1600

#define GRID   1024
#define WAVES  4
#define NWAVE  (GRID*WAVES)       // 4096 waves
#define PAIRS  16                 // 32 rows/wave, software-pipelined pairs, exact

// Hazard-safe cross-lane swap-sums (R16-proven; inline-asm permlane corrupted
// data in dense schedules — R13 vs R16 bisect).
__device__ __forceinline__ v2f swap32_sum(v2f lo, v2f hi, int lane) {
    bool up = (lane & 32) != 0;
    v2f keep = up ? hi : lo;
    v2f send = up ? lo : hi;
    v2f r;
    r[0] = keep[0] + __shfl_xor(send[0], 32);
    r[1] = keep[1] + __shfl_xor(send[1], 32);
    return r;
}
__device__ __forceinline__ v2f swap16_sum(v2f lo, v2f hi, int lane) {
    bool up = (lane & 16) != 0;
    v2f keep = up ? hi : lo;
    v2f send = up ? lo : hi;
    v2f r;
    r[0] = keep[0] + __shfl_xor(send[0], 16);
    r[1] = keep[1] + __shfl_xor(send[1], 16);
    return r;
}
// DPP cross-lane (builtins — compiler handles hazards)
template <int CTRL>
__device__ __forceinline__ float dppf(float x) {
    return __builtin_bit_cast(float, __builtin_amdgcn_update_dpp(
        0, __builtin_bit_cast(int, x), CTRL, 0xF, 0xF, true));
}
template <int CTRL>
__device__ __forceinline__ int dppi(int x) {
    return __builtin_amdgcn_update_dpp(0, x, CTRL, 0xF, 0xF, true);
}
// full 16-lane sum (butterfly over lane bits 0..3)
__device__ __forceinline__ float red16(float v) {
    v += dppf<0xB1>(v);    // quad_perm xor1
    v += dppf<0x4E>(v);    // quad_perm xor2
    v += dppf<0x141>(v);   // row_half_mirror
    v += dppf<0x140>(v);   // row_mirror
    return v;
}
__device__ __forceinline__ void wave_fence() {
    asm volatile("s_waitcnt lgkmcnt(0)" ::: "memory");
    __builtin_amdgcn_sched_barrier(0);  // rule #18
}

__device__ __forceinline__ float reduce_scatter(v2f P[8], int lane) {
    v2f Q[4];
#pragma unroll
    for (int r = 0; r < 4; ++r)
        Q[r] = swap32_sum(P[r], P[r+4], lane);
    v2f S0 = swap16_sum(Q[0], Q[2], lane);
    v2f S1 = swap16_sum(Q[1], Q[3], lane);
    float a = red16(S0[0]), b = red16(S0[1]);
    float c = red16(S1[0]), d = red16(S1[1]);
    float lo = (lane & 1) ? b : a;
    float hi = (lane & 1) ? d : c;
    return (lane & 2) ? hi : lo;
}

// full per-row chain: proj partials -> reduce-scatter -> searchsorted ->
// CDF interp -> barycenter inverse-CDF -> coeff = xm - z
__device__ __forceinline__ float chain_row(v4f x, int dom, const v2f wTo[4][8],
                                           const float* sEB_, const float* sCDF_,
                                           const float* bqk, int k, int ec, int lane) {
    const float* ebRow = &sEB_[(dom*KP + k)*(NB+1)];
    float e[8];
#pragma unroll
    for (int t = 0; t < 8; ++t) e[t] = ebRow[8*ec + t];

    v2f P[8];
#pragma unroll
    for (int q = 0; q < 8; ++q) P[q] = (v2f){0.f, 0.f};
#pragma unroll
    for (int j = 0; j < 4; ++j) {
        v2f xj = {x[j], x[j]};
#pragma unroll
        for (int q = 0; q < 8; ++q) P[q] += xj * wTo[j][q];
    }
    float xm = reduce_scatter(P, lane);

    int cnt = (e[0] <= xm) + (e[1] <= xm) + (e[2] <= xm) + (e[3] <= xm)
            + (e[4] <= xm) + (e[5] <= xm) + (e[6] <= xm) + (e[7] <= xm);
    cnt += dppi<0x124>(cnt);   // row_ror:4
    cnt += dppi<0x128>(cnt);   // row_ror:8
    int i0 = min(max(cnt - 1, 0), NB - 1);
    float x0 = ebRow[i0], x1 = ebRow[i0+1];
    const float* cfRow = &sCDF_[(dom*KP + k)*(NB+1)];
    float f0 = cfRow[i0], f1 = cfRow[i0+1];
    float t  = fminf(fmaxf(__fdividef(xm - x0, x1 - x0), 0.f), 1.f);
    float u  = f0 + t * (f1 - f0);
    float posv = fminf(fmaxf(u, 0.f), 1.f) * (float)(GG - 1);
    int jj = min((int)posv, GG - 2);
    float ttf = posv - (float)jj;
    float b0 = bqk[jj], b1 = bqk[jj+1];
    return xm - (b0*(1.f - ttf) + b1*ttf);
}

__device__ __forceinline__ void load_coeffs(const float* cb, v2f c2[8]) {
#pragma unroll
    for (int q = 0; q < 4; ++q) {
        v4f cv4 = *reinterpret_cast<const v4f*>(&cb[4*q]);   // broadcast read
        c2[2*q]   = (v2f){cv4[0], cv4[1]};
        c2[2*q+1] = (v2f){cv4[2], cv4[3]};
    }
}
__device__ __forceinline__ void emit_row(v4f x, const v2f c2[8], const v2f wTo[4][8],
                                         float* op) {
    v4f o4;
#pragma unroll
    for (int j = 0; j < 4; ++j) {
        v2f a = c2[0] * wTo[j][0];
#pragma unroll
        for (int q = 1; q < 8; ++q) a += c2[q] * wTo[j][q];
        o4[j] = x[j] - (a[0] + a[1]);
    }
    *reinterpret_cast<v4f*>(op) = o4;
}

__global__ __launch_bounds__(256, 4)   // proven-safe budget: no scratch
void inb_kernel(const float* __restrict__ X, const int* __restrict__ y,
                const float* __restrict__ wT, const float* __restrict__ be,
                const float* __restrict__ cv, const float* __restrict__ bq,
                float* __restrict__ out)
{
    // LDS: 16896 + 16896 + 6400 + 512 = 40704 B -> 4 blocks/CU (== R11)
    __shared__ alignas(16) float sEB[EB_N];
    __shared__ alignas(16) float sCDF[EB_N];
    __shared__ alignas(16) float sBARY[BARY_N];
    __shared__ alignas(16) float sCOEFF[WAVES][32];

    const int tid = threadIdx.x;
    for (int i = tid; i < EB_N; i += 256) { sEB[i] = be[i]; sCDF[i] = cv[i]; }
    for (int i = tid; i < BARY_N; i += 256) sBARY[i] = bq[i];
    __syncthreads();

    const int lane = tid & 63;
    const int wid  = tid >> 6;
    const int k  = ((lane & 48) >> 2) | (lane & 3);   // k in lane bits 0,1,4,5
    const int ec = (lane >> 2) & 3;                   // edge-chunk in bits 2,3

    v2f wTo[4][8];
#pragma unroll
    for (int j = 0; j < 4; ++j) {
        const v4f* wrow = reinterpret_cast<const v4f*>(&wT[(4*lane + j)*KP]);
#pragma unroll
        for (int q = 0; q < 4; ++q) {
            v4f v = wrow[q];
            wTo[j][2*q]   = (v2f){v[0], v[1]};
            wTo[j][2*q+1] = (v2f){v[2], v[3]};
        }
    }

    float* cobuf = sCOEFF[wid];
    const float* bqk = &sBARY[k*GG];
    const int gwave = blockIdx.x * WAVES + wid;
    const int xoff  = 4*lane;

    // ---------------- prologue: pair 0 ----------------
    v4f xA_c = *reinterpret_cast<const v4f*>(&X[(size_t)gwave*DIM + xoff]);
    v4f xB_c = *reinterpret_cast<const v4f*>(&X[(size_t)(gwave + NWAVE)*DIM + xoff]);
    int dA_c = y[gwave], dB_c = y[gwave + NWAVE];
    // prefetch pair 1
    v4f xA_n = *reinterpret_cast<const v4f*>(&X[(size_t)(gwave + 2*NWAVE)*DIM + xoff]);
    v4f xB_n = *reinterpret_cast<const v4f*>(&X[(size_t)(gwave + 3*NWAVE)*DIM + xoff]);
    int dA_n = y[gwave + 2*NWAVE], dB_n = y[gwave + 3*NWAVE];

    {
        float cA = chain_row(xA_c, dA_c, wTo, sEB, sCDF, bqk, k, ec, lane);
        float cB = chain_row(xB_c, dB_c, wTo, sEB, sCDF, bqk, k, ec, lane);
        if (ec < 2) cobuf[ec*16 + k] = (ec == 0) ? cA : cB;
    }
    v4f xA_o = xA_c, xB_o = xB_c;
    int r_o = gwave;
    xA_c = xA_n; xB_c = xB_n; dA_c = dA_n; dB_c = dB_n;

    // ---------------- pipelined main loop ----------------
    for (int it = 1; it < PAIRS; ++it) {
        const int rA = gwave + (2*it)*NWAVE;

        wave_fence();   // completes pair it-1's cobuf write (issued last iter: ~free)

        // coeff reads for pair it-1 (issue early; independent of the chain)
        v2f c2A[8], c2B[8];
        load_coeffs(cobuf,      c2A);
        load_coeffs(cobuf + 16, c2B);

        // prefetch pair it+1 (clamped on last iteration)
        int pfA = (it + 1 < PAIRS) ? rA + 2*NWAVE : rA;
        v4f xA_p = *reinterpret_cast<const v4f*>(&X[(size_t)pfA*DIM + xoff]);
        v4f xB_p = *reinterpret_cast<const v4f*>(&X[(size_t)(pfA + NWAVE)*DIM + xoff]);
        int dA_p = y[pfA], dB_p = y[pfA + NWAVE];

        // compute chain for pair it
        float cA = chain_row(xA_c, dA_c, wTo, sEB, sCDF, bqk, k, ec, lane);
        float cB = chain_row(xB_c, dB_c, wTo, sEB, sCDF, bqk, k, ec, lane);
        // write AFTER the c2 reads in program order: same-wave DS ops execute
        // in order, so the reads above return pair it-1's values
        if (ec < 2) cobuf[ec*16 + k] = (ec == 0) ? cA : cB;

        // emit pair it-1 (overlaps the next iteration's fence-free region)
        emit_row(xA_o, c2A, wTo, &out[(size_t)r_o*DIM + xoff]);
        emit_row(xB_o, c2B, wTo, &out[(size_t)(r_o + NWAVE)*DIM + xoff]);

        xA_o = xA_c; xB_o = xB_c; r_o = rA;
        xA_c = xA_p; xB_c = xB_p; dA_c = dA_p; dB_c = dB_p;
    }

    // ---------------- epilogue: pair PAIRS-1 ----------------
    wave_fence();
    v2f c2A[8], c2B[8];
    load_coeffs(cobuf,      c2A);
    load_coeffs(cobuf + 16, c2B);
    emit_row(xA_o, c2A, wTo, &out[(size_t)r_o*DIM + xoff]);
    emit_row(xB_o, c2B, wTo, &out[(size_t)(r_o + NWAVE)*DIM + xoff]);
}

extern "C" void kernel_launch(void* const* d_in, const int* in_sizes, int n_in,
                              void* d_out, int out_size, void* d_ws, size_t ws_size,
                              hipStream_t stream) {
    const float* X  = (const float*)d_in[0];
    const int*   y  = (const int*)  d_in[1];
    const float* wT = (const float*)d_in[2];
    const float* be = (const float*)d_in[3];
    const float* cv = (const float*)d_in[4];
    const float* bq = (const float*)d_in[5];
    float* out = (float*)d_out;
    hipLaunchKernelGGL(inb_kernel, dim3(GRID), dim3(256), 0, stream,
                       X, y, wT, be, cv, bq, out);
}

// Round 19
// 75.220 us; speedup vs baseline: 2.8464x; 2.8464x over previous
//
#include <hip/hip_runtime.h>

typedef float v2f __attribute__((ext_vector_type(2)));
typedef float v4f __attribute__((ext_vector_type(4)));

#define N_ROWS 131072
#define DIM    256
#define KP     16
#define NDOM   8
#define NB     32      // bins
#define GG     100     // barycenter grid

#define EB_N   (NDOM*KP*(NB+1))   // 4224 floats
#define BARY_N (KP*GG)            // 1600

#define GRID   1024
#define WAVES  4
#define NWAVE  (GRID*WAVES)       // 4096 waves
#define PAIRS  16                 // 32 rows/wave, 2 rows per iteration, exact

// Hazard-safe cross-lane swap-sums (R16-proven; inline-asm permlane corrupted
// data in dense schedules — R13 vs R16 bisect).
__device__ __forceinline__ v2f swap32_sum(v2f lo, v2f hi, int lane) {
    bool up = (lane & 32) != 0;
    v2f keep = up ? hi : lo;
    v2f send = up ? lo : hi;
    v2f r;
    r[0] = keep[0] + __shfl_xor(send[0], 32);
    r[1] = keep[1] + __shfl_xor(send[1], 32);
    return r;
}
__device__ __forceinline__ v2f swap16_sum(v2f lo, v2f hi, int lane) {
    bool up = (lane & 16) != 0;
    v2f keep = up ? hi : lo;
    v2f send = up ? lo : hi;
    v2f r;
    r[0] = keep[0] + __shfl_xor(send[0], 16);
    r[1] = keep[1] + __shfl_xor(send[1], 16);
    return r;
}
// DPP cross-lane (builtins — compiler handles hazards)
template <int CTRL>
__device__ __forceinline__ float dppf(float x) {
    return __builtin_bit_cast(float, __builtin_amdgcn_update_dpp(
        0, __builtin_bit_cast(int, x), CTRL, 0xF, 0xF, true));
}
template <int CTRL>
__device__ __forceinline__ int dppi(int x) {
    return __builtin_amdgcn_update_dpp(0, x, CTRL, 0xF, 0xF, true);
}
// full 16-lane sum, every lane gets the total (butterfly over lane bits 0..3)
__device__ __forceinline__ float red16(float v) {
    v += dppf<0xB1>(v);    // quad_perm xor1
    v += dppf<0x4E>(v);    // quad_perm xor2
    v += dppf<0x141>(v);   // row_half_mirror
    v += dppf<0x140>(v);   // row_mirror
    return v;
}
__device__ __forceinline__ void wave_fence() {
    asm volatile("s_waitcnt lgkmcnt(0)" ::: "memory");
    __builtin_amdgcn_sched_barrier(0);  // rule #18
}

// plain v2f arithmetic: compiler emits v_pk_fma_f32 and schedules freely
__device__ __forceinline__ void proj_row(v4f x, const v2f wTo[4][8], v2f P[8]) {
#pragma unroll
    for (int q = 0; q < 8; ++q) P[q] = (v2f){0.f, 0.f};
#pragma unroll
    for (int j = 0; j < 4; ++j) {
        v2f xj = {x[j], x[j]};
#pragma unroll
        for (int q = 0; q < 8; ++q) P[q] += xj * wTo[j][q];
    }
}

// P[8] per-lane partials -> xm for this lane's k = 8*b5+4*b4+(lane&3)
__device__ __forceinline__ float reduce_scatter(v2f P[8], int lane) {
    v2f Q[4];
#pragma unroll
    for (int r = 0; r < 4; ++r)
        Q[r] = swap32_sum(P[r], P[r+4], lane);
    v2f S0 = swap16_sum(Q[0], Q[2], lane);
    v2f S1 = swap16_sum(Q[1], Q[3], lane);
    float a = red16(S0[0]), b = red16(S0[1]);
    float c = red16(S1[0]), d = red16(S1[1]);
    float lo = (lane & 1) ? b : a;
    float hi = (lane & 1) ? d : c;
    return (lane & 2) ? hi : lo;
}

// count-searchsorted + CDF interp + barycenter inverse-CDF -> coeff = xm - z
__device__ __forceinline__ float quantile_map(float xm, const float* ebRow,
                                              const float* cfRow, const float* bqk,
                                              const float e[8]) {
    int cnt = (e[0] <= xm) + (e[1] <= xm) + (e[2] <= xm) + (e[3] <= xm)
            + (e[4] <= xm) + (e[5] <= xm) + (e[6] <= xm) + (e[7] <= xm);
    cnt += dppi<0x124>(cnt);   // row_ror:4 — sums ec groups, keeps lane bits 0,1
    cnt += dppi<0x128>(cnt);   // row_ror:8
    int i0 = min(max(cnt - 1, 0), NB - 1);
    float x0 = ebRow[i0], x1 = ebRow[i0+1];
    float f0 = cfRow[i0], f1 = cfRow[i0+1];
    float t  = fminf(fmaxf(__fdividef(xm - x0, x1 - x0), 0.f), 1.f);
    float u  = f0 + t * (f1 - f0);
    float posv = fminf(fmaxf(u, 0.f), 1.f) * (float)(GG - 1);
    int jj = min((int)posv, GG - 2);
    float ttf = posv - (float)jj;
    float b0 = bqk[jj], b1 = bqk[jj+1];
    return xm - (b0*(1.f - ttf) + b1*ttf);
}

__device__ __forceinline__ void out_row(v4f x, const float* cb, const v2f wTo[4][8],
                                        float* op) {
    v2f c2[8];
#pragma unroll
    for (int q = 0; q < 4; ++q) {
        v4f cv4 = *reinterpret_cast<const v4f*>(&cb[4*q]);   // broadcast read
        c2[2*q]   = (v2f){cv4[0], cv4[1]};
        c2[2*q+1] = (v2f){cv4[2], cv4[3]};
    }
    v4f o4;
#pragma unroll
    for (int j = 0; j < 4; ++j) {
        v2f a = c2[0] * wTo[j][0];
#pragma unroll
        for (int q = 1; q < 8; ++q) a += c2[q] * wTo[j][q];
        o4[j] = x[j] - (a[0] + a[1]);
    }
    *reinterpret_cast<v4f*>(op) = o4;
}

// amdgpu_waves_per_eu(4,4): pin occupancy to exactly 4 waves/EU so the
// allocator spends the full 512/4 = 128 VGPR budget instead of its default
// 64-reg/8-wave heuristic (observed: 64 VGPR + wT re-loads/spills in R9-R18).
__global__ __attribute__((amdgpu_flat_work_group_size(256, 256),
                          amdgpu_waves_per_eu(4, 4)))
void inb_kernel(const float* __restrict__ X, const int* __restrict__ y,
                const float* __restrict__ wT, const float* __restrict__ be,
                const float* __restrict__ cv, const float* __restrict__ bq,
                float* __restrict__ out)
{
    // LDS: 16896 + 16896 + 6400 + 512 = 40704 B -> 4 blocks/CU
    __shared__ alignas(16) float sEB[EB_N];
    __shared__ alignas(16) float sCDF[EB_N];
    __shared__ alignas(16) float sBARY[BARY_N];
    __shared__ alignas(16) float sCOEFF[WAVES][32];

    const int tid = threadIdx.x;
    for (int i = tid; i < EB_N; i += 256) { sEB[i] = be[i]; sCDF[i] = cv[i]; }
    for (int i = tid; i < BARY_N; i += 256) sBARY[i] = bq[i];
    __syncthreads();

    const int lane = tid & 63;
    const int wid  = tid >> 6;
    const int k  = ((lane & 48) >> 2) | (lane & 3);   // k in lane bits 0,1,4,5
    const int ec = (lane >> 2) & 3;                   // edge-chunk in bits 2,3

    // wT rows 4l..4l+3, all 16 k — resident at the pinned 128-VGPR budget
    v2f wTo[4][8];
#pragma unroll
    for (int j = 0; j < 4; ++j) {
        const v4f* wrow = reinterpret_cast<const v4f*>(&wT[(4*lane + j)*KP]);
#pragma unroll
        for (int q = 0; q < 4; ++q) {
            v4f v = wrow[q];
            wTo[j][2*q]   = (v2f){v[0], v[1]};
            wTo[j][2*q+1] = (v2f){v[2], v[3]};
        }
    }

    float* cobuf = sCOEFF[wid];
    const float* bqk = &sBARY[k*GG];
    const int gwave = blockIdx.x * WAVES + wid;
    const int xoff  = 4*lane;

    v4f xA = *reinterpret_cast<const v4f*>(&X[(size_t)gwave*DIM + xoff]);
    v4f xB = *reinterpret_cast<const v4f*>(&X[(size_t)(gwave + NWAVE)*DIM + xoff]);
    int dA = y[gwave], dB = y[gwave + NWAVE];

    for (int it = 0; it < PAIRS; ++it) {
        const int rA = gwave + (2*it)*NWAVE;
        const int rB = rA + NWAVE;

        // edge reads first (depend only on prefetched dom)
        const float* ebA = &sEB[(dA*KP + k)*(NB+1)];
        const float* ebB = &sEB[(dB*KP + k)*(NB+1)];
        float eA[8], eB[8];
#pragma unroll
        for (int t = 0; t < 8; ++t) { eA[t] = ebA[8*ec + t]; eB[t] = ebB[8*ec + t]; }

        // prefetch next pair (clamped; unused on last iter)
        int nA = rA + 2*NWAVE; if (nA >= N_ROWS) nA = rA;
        int nB = nA + NWAVE;   if (nB >= N_ROWS) nB = rA;
        int dA_n = y[nA], dB_n = y[nB];
        v4f xA_n = *reinterpret_cast<const v4f*>(&X[(size_t)nA*DIM + xoff]);
        v4f xB_n = *reinterpret_cast<const v4f*>(&X[(size_t)nB*DIM + xoff]);

        v2f PA[8], PB[8];
        proj_row(xA, wTo, PA);
        proj_row(xB, wTo, PB);

        float xmA = reduce_scatter(PA, lane);
        float xmB = reduce_scatter(PB, lane);

        float cA = quantile_map(xmA, ebA, &sCDF[(dA*KP + k)*(NB+1)], bqk, eA);
        float cB = quantile_map(xmB, ebB, &sCDF[(dB*KP + k)*(NB+1)], bqk, eB);

        if (ec < 2) cobuf[ec*16 + k] = (ec == 0) ? cA : cB;   // 32 lanes, 32 banks
        wave_fence();

        out_row(xA, cobuf,      wTo, &out[(size_t)rA*DIM + xoff]);
        out_row(xB, cobuf + 16, wTo, &out[(size_t)rB*DIM + xoff]);

        xA = xA_n; xB = xB_n; dA = dA_n; dB = dB_n;
    }
}

extern "C" void kernel_launch(void* const* d_in, const int* in_sizes, int n_in,
                              void* d_out, int out_size, void* d_ws, size_t ws_size,
                              hipStream_t stream) {
    const float* X  = (const float*)d_in[0];
    const int*   y  = (const int*)  d_in[1];
    const float* wT = (const float*)d_in[2];
    const float* be = (const float*)d_in[3];
    const float* cv = (const float*)d_in[4];
    const float* bq = (const float*)d_in[5];
    float* out = (float*)d_out;
    hipLaunchKernelGGL(inb_kernel, dim3(GRID), dim3(256), 0, stream,
                       X, y, wT, be, cv, bq, out);
}